// Round 24
// baseline (3527.457 us; speedup 1.0000x reference)
//
#include <hip/hip_runtime.h>
#include <hip/hip_bf16.h>

// MMGCRN on MFMA. Graph: 128n x 128j x plane blocks, 64x64 wave tiles built
// from 16x16 MFMAs (0.5 ds_reads/MFMA); epilogue gathers output through LDS
// for full-cacheline global writes. slice2 = M@X - X (M=2S^2, exact -I).
// Dense: A(bf16) x W(bf16), 64-row tiles BK=32, GRU fused; dec-up fuses proj.
// Agh slice-0 incremental. XOR-swizzled LDS. B=64,T=12,N=1024,HOR=12.
constexpr int B_ = 64, T_ = 12, NN = 1024, HOR_ = 12;

typedef __attribute__((ext_vector_type(8))) short short8;   // 8 bf16 (4 VGPRs)
typedef __attribute__((ext_vector_type(4))) short short4v;  // 4 bf16 (8B)
typedef __attribute__((ext_vector_type(4))) float f32x4;    // MFMA C/D frag
typedef unsigned short ushort_t;

static __device__ inline ushort_t f2bh(float v) {
  __hip_bfloat16 h = __float2bfloat16(v);
  return *reinterpret_cast<ushort_t*>(&h);
}
static __device__ inline float bh2f(ushort_t u) {
  __hip_bfloat16 h = *reinterpret_cast<__hip_bfloat16*>(&u);
  return __bfloat162float(h);
}
static __device__ inline void split_bf16(float v, ushort_t& hi, ushort_t& lo) {
  hi = f2bh(v);
  lo = f2bh(v - bh2f(hi));
}

// async global->LDS, 16B per lane (LDS dest = wave-uniform base + lane*16).
static __device__ inline void gload_lds16(const ushort_t* g, ushort_t* l) {
  __builtin_amdgcn_global_load_lds(
      (const __attribute__((address_space(1))) unsigned int*)g,
      (__attribute__((address_space(3))) unsigned int*)l, 16, 0, 0);
}

// ---------------------------------------------------------------------------
// C = A (M x Kd) @ B (Ncol x Kd)^T, row-major, 64x64 tile, 4x4/thread. fp32.
// (only the tiny emb syrk, Kd=8)
__global__ void gemm_nt_kernel(const float* __restrict__ A, const float* __restrict__ Bm,
                               float* __restrict__ C, int Ncol, int Kd) {
  __shared__ float As[16][68];
  __shared__ float Bs[16][68];
  const int bm = blockIdx.y * 64, bn = blockIdx.x * 64;
  const int tid = threadIdx.x;
  const int tx = tid & 15, ty = tid >> 4;
  float acc[4][4] = {};
  for (int k0 = 0; k0 < Kd; k0 += 16) {
#pragma unroll
    for (int r = 0; r < 4; ++r) {
      const int m = (tid >> 4) + r * 16;
      const int kk = tid & 15;
      const int k = k0 + kk;
      As[kk][m] = (k < Kd) ? A[(size_t)(bm + m) * Kd + k] : 0.f;
      Bs[kk][m] = (k < Kd) ? Bm[(size_t)(bn + m) * Kd + k] : 0.f;
    }
    __syncthreads();
#pragma unroll
    for (int kk = 0; kk < 16; ++kk) {
      float a[4], b[4];
#pragma unroll
      for (int i = 0; i < 4; ++i) a[i] = As[kk][ty * 4 + i];
#pragma unroll
      for (int j = 0; j < 4; ++j) b[j] = Bs[kk][tx * 4 + j];
#pragma unroll
      for (int i = 0; i < 4; ++i)
#pragma unroll
        for (int j = 0; j < 4; ++j) acc[i][j] += a[i] * b[j];
    }
    __syncthreads();
  }
#pragma unroll
  for (int i = 0; i < 4; ++i)
#pragma unroll
    for (int j = 0; j < 4; ++j)
      C[(size_t)(bm + ty * 4 + i) * Ncol + bn + tx * 4 + j] = acc[i][j];
}

// ---------------------------------------------------------------------------
// In-place row softmax(relu(x)) over 1024 cols; also emits bf16 hi/lo split.
__global__ void relu_softmax_kernel(float* __restrict__ S, ushort_t* __restrict__ Sh,
                                    ushort_t* __restrict__ Sl) {
  const int row = blockIdx.x;
  float* r = S + (size_t)row * NN;
  const int tid = threadIdx.x;  // 256
  float v[4];
  float mx = 0.f;
#pragma unroll
  for (int j = 0; j < 4; ++j) {
    float xv = fmaxf(r[tid + j * 256], 0.f);
    v[j] = xv;
    mx = fmaxf(mx, xv);
  }
#pragma unroll
  for (int off = 1; off < 64; off <<= 1) mx = fmaxf(mx, __shfl_xor(mx, off));
  __shared__ float sred[4];
  const int wv = tid >> 6;
  if ((tid & 63) == 0) sred[wv] = mx;
  __syncthreads();
  mx = fmaxf(fmaxf(sred[0], sred[1]), fmaxf(sred[2], sred[3]));
  __syncthreads();
  float s = 0.f;
#pragma unroll
  for (int j = 0; j < 4; ++j) { v[j] = expf(v[j] - mx); s += v[j]; }
#pragma unroll
  for (int off = 1; off < 64; off <<= 1) s += __shfl_xor(s, off);
  if ((tid & 63) == 0) sred[wv] = s;
  __syncthreads();
  s = sred[0] + sred[1] + sred[2] + sred[3];
  const float inv = 1.f / s;
#pragma unroll
  for (int j = 0; j < 4; ++j) {
    const float sv = v[j] * inv;
    const size_t e = (size_t)row * NN + tid + j * 256;
    r[tid + j * 256] = sv;
    ushort_t hi, lo;
    split_bf16(sv, hi, lo);
    Sh[e] = hi;
    Sl[e] = lo;
  }
}

// ---------------------------------------------------------------------------
// ST = S^T, bf16 hi/lo split. LDS-tiled 64x64, both sides coalesced.
__global__ void st_kernel(const float* __restrict__ S, ushort_t* __restrict__ STh,
                          ushort_t* __restrict__ STl) {
  __shared__ float tile[64][65];
  const int bx = blockIdx.x * 64, by = blockIdx.y * 64;
  const int tid = threadIdx.x;
  const int cl = tid & 63, rq = tid >> 6;
#pragma unroll
  for (int r = 0; r < 16; ++r) {
    const int rr = rq + r * 4;
    tile[rr][cl] = S[(size_t)(by + rr) * NN + bx + cl];
  }
  __syncthreads();
#pragma unroll
  for (int r = 0; r < 16; ++r) {
    const int rr = rq + r * 4;
    const float v = tile[cl][rr];  // = S[by+cl][bx+rr]
    ushort_t hi, lo;
    split_bf16(v, hi, lo);
    STh[(size_t)(bx + rr) * NN + by + cl] = hi;
    STl[(size_t)(bx + rr) * NN + by + cl] = lo;
  }
}

// ---------------------------------------------------------------------------
// M = 2*S@S on MFMA, bf16x3 (A=S1 hi/lo, B=ST hi/lo), out single bf16 plane.
// Tile 32n x 64j, BK=64, grid (16,32). XOR-swizzled LDS.
__global__ void cheb_mfma_kernel(const ushort_t* __restrict__ S1h,
                                 const ushort_t* __restrict__ S1l,
                                 const ushort_t* __restrict__ STh,
                                 const ushort_t* __restrict__ STl,
                                 ushort_t* __restrict__ Mh) {
  __shared__ __align__(16) ushort_t sA[2 * 32 * 64];  // 8 KB
  __shared__ __align__(16) ushort_t sB[2 * 64 * 64];  // 16 KB
  const int bj = blockIdx.x * 64, bn = blockIdx.y * 32;
  const int tid = threadIdx.x;
  const int w = tid >> 6, lane = tid & 63;
  const int row = lane & 15, kq = lane >> 4;
  const int srow8 = lane >> 3, sslot = lane & 7;
  f32x4 acc[2] = {};
  for (int k0 = 0; k0 < NN; k0 += 64) {
#pragma unroll
    for (int t2 = 0; t2 < 2; ++t2) {  // A: 8 chunks, wave stages 2
      const int c = w + t2 * 4, p = c >> 2, i = c & 3;
      const int grow = i * 8 + srow8;
      const int gch = sslot ^ (grow & 7);
      const ushort_t* src = (p ? S1l : S1h) + (size_t)(bn + grow) * NN + k0 + gch * 8;
      gload_lds16(src, sA + p * 2048 + i * 512);
    }
#pragma unroll
    for (int t2 = 0; t2 < 4; ++t2) {  // B: 16 chunks, wave stages 4
      const int c2 = w + t2 * 4, p = c2 >> 3, rb = c2 & 7;
      const int grow = rb * 8 + srow8;
      const int gch = sslot ^ (grow & 7);
      const ushort_t* src = (p ? STl : STh) + (size_t)(bj + grow) * NN + k0 + gch * 8;
      gload_lds16(src, sB + p * 4096 + rb * 512);
    }
    __syncthreads();
#pragma unroll
    for (int kk = 0; kk < 2; ++kk) {
      const int rB = w * 16 + row;
      const int chB = ((kk * 4 + kq) ^ (rB & 7)) * 8;
      const short8 bh = *(const short8*)(sB + rB * 64 + chB);
      const short8 bl = *(const short8*)(sB + 4096 + rB * 64 + chB);
#pragma unroll
      for (int mt = 0; mt < 2; ++mt) {
        const int rA = mt * 16 + row;
        const int chA = ((kk * 4 + kq) ^ (rA & 7)) * 8;
        const short8 ah = *(const short8*)(sA + rA * 64 + chA);
        const short8 al = *(const short8*)(sA + 2048 + rA * 64 + chA);
        acc[mt] = __builtin_amdgcn_mfma_f32_16x16x32_bf16(ah, bh, acc[mt], 0, 0, 0);
        acc[mt] = __builtin_amdgcn_mfma_f32_16x16x32_bf16(ah, bl, acc[mt], 0, 0, 0);
        acc[mt] = __builtin_amdgcn_mfma_f32_16x16x32_bf16(al, bh, acc[mt], 0, 0, 0);
      }
    }
    __syncthreads();
  }
  const int j = bj + w * 16 + row;
#pragma unroll
  for (int mt = 0; mt < 2; ++mt) {
    const int node0 = bn + mt * 16 + kq * 4;
#pragma unroll
    for (int r = 0; r < 4; ++r)
      Mh[(size_t)(node0 + r) * NN + j] = f2bh(2.f * acc[mt][r]);
  }
}

// ---------------------------------------------------------------------------
// S1out = WE @ WE^T on MFMA, bf16x3 (WE hi/lo, K=512), fp32 out.
// Tile 32 x 64, BK=64, grid (16, 32). XOR-swizzled LDS.
__global__ void we_syrk_kernel(const ushort_t* __restrict__ WEh,
                               const ushort_t* __restrict__ WEl,
                               float* __restrict__ S1out) {
  __shared__ __align__(16) ushort_t sA[2 * 32 * 64];  // 8 KB
  __shared__ __align__(16) ushort_t sB[2 * 64 * 64];  // 16 KB
  const int bj = blockIdx.x * 64, bn = blockIdx.y * 32;
  const int tid = threadIdx.x;
  const int w = tid >> 6, lane = tid & 63;
  const int row = lane & 15, kq = lane >> 4;
  const int srow8 = lane >> 3, sslot = lane & 7;
  f32x4 acc[2] = {};
  for (int k0 = 0; k0 < 512; k0 += 64) {
#pragma unroll
    for (int t2 = 0; t2 < 6; ++t2) {  // 24 chunks: 8 A + 16 B
      const int cid = w + t2 * 4;
      if (cid < 8) {
        const int p = cid >> 2, i = cid & 3;
        const int grow = i * 8 + srow8;
        const int gch = sslot ^ (grow & 7);
        const ushort_t* src = (p ? WEl : WEh) + (size_t)(bn + grow) * 512 + k0 + gch * 8;
        gload_lds16(src, sA + p * 2048 + i * 512);
      } else {
        const int c2 = cid - 8, p = c2 >> 3, rb = c2 & 7;
        const int grow = rb * 8 + srow8;
        const int gch = sslot ^ (grow & 7);
        const ushort_t* src = (p ? WEl : WEh) + (size_t)(bj + grow) * 512 + k0 + gch * 8;
        gload_lds16(src, sB + p * 4096 + rb * 512);
      }
    }
    __syncthreads();
#pragma unroll
    for (int kk = 0; kk < 2; ++kk) {
      const int rB = w * 16 + row;
      const int chB = ((kk * 4 + kq) ^ (rB & 7)) * 8;
      const short8 bh = *(const short8*)(sB + rB * 64 + chB);
      const short8 bl = *(const short8*)(sB + 4096 + rB * 64 + chB);
#pragma unroll
      for (int mt = 0; mt < 2; ++mt) {
        const int rA = mt * 16 + row;
        const int chA = ((kk * 4 + kq) ^ (rA & 7)) * 8;
        const short8 ah = *(const short8*)(sA + rA * 64 + chA);
        const short8 al = *(const short8*)(sA + 2048 + rA * 64 + chA);
        acc[mt] = __builtin_amdgcn_mfma_f32_16x16x32_bf16(ah, bh, acc[mt], 0, 0, 0);
        acc[mt] = __builtin_amdgcn_mfma_f32_16x16x32_bf16(ah, bl, acc[mt], 0, 0, 0);
        acc[mt] = __builtin_amdgcn_mfma_f32_16x16x32_bf16(al, bh, acc[mt], 0, 0, 0);
      }
    }
    __syncthreads();
  }
  const int j = bj + w * 16 + row;
#pragma unroll
  for (int mt = 0; mt < 2; ++mt) {
    const int node0 = bn + mt * 16 + kq * 4;
#pragma unroll
    for (int r = 0; r < 4; ++r)
      S1out[(size_t)(node0 + r) * NN + j] = acc[mt][r];
  }
}

// ---------------------------------------------------------------------------
// Wt[no][k] = W[k][no], plain bf16, zero-padded to [NOP][KP].
__global__ void wt_kernel(const float* __restrict__ W, ushort_t* __restrict__ Wth,
                          int KK, int NO, int KP, int NOP) {
  const int e = blockIdx.x * 256 + threadIdx.x;
  if (e >= NOP * KP) return;
  const int no = e / KP, k = e - no * KP;
  const float v = (no < NO && k < KK) ? W[(size_t)k * NO + no] : 0.f;
  Wth[e] = f2bh(v);
}

// ---------------------------------------------------------------------------
// prep (t=0 only): build cell input; write Agh slice0 + XTh.
// MODE 0: enc build [x_0, h]; MODE 2: dec build [go, yc_0, h].
template <int C, int KP, int MODE>
__global__ void prep_kernel(const float* __restrict__ src0, const float* __restrict__ src1,
                            const float* __restrict__ hst,
                            ushort_t* __restrict__ Agh, ushort_t* __restrict__ XTh) {
  __shared__ float tile[64][65];
  const int bj = blockIdx.x * 64, bn = blockIdx.y * 64;
  const int tid = threadIdx.x;
  const int jl = tid & 63, nq = tid >> 6;
  const int j = bj + jl;
  const int b = j / C, c = j - b * C;
#pragma unroll
  for (int r = 0; r < 16; ++r) {
    const int node = bn + nq + r * 4;
    const int idx = node * 64 + b;
    float v;
    if (MODE == 0) {
      v = (c == 0) ? src0[((size_t)b * T_) * NN + node]
                   : hst[(size_t)idx * 64 + (c - 1)];
    } else {
      v = (c == 0) ? src0[idx]
        : (c == 1) ? src1[((size_t)b * HOR_) * NN + node]
                   : hst[(size_t)idx * 96 + (c - 2)];
    }
    tile[nq + r * 4][jl] = v;
    Agh[(size_t)idx * KP + c] = f2bh(v);
  }
  __syncthreads();
  const int nl = tid & 63, jq = tid >> 6;
#pragma unroll
  for (int r = 0; r < 16; ++r) {
    const int jj = bj + jq + r * 4;
    XTh[(size_t)jj * NN + bn + nl] = f2bh(tile[nl][jq + r * 4]);
  }
}

// ---------------------------------------------------------------------------
// xt: transpose Agh slice0 -> XTh. WITHX: c==0 comes from x[t] (also stored).
template <int C, int KP, bool WITHX>
__global__ void xt_kernel(ushort_t* __restrict__ Agh, ushort_t* __restrict__ XTh,
                          const float* __restrict__ x, int t) {
  __shared__ ushort_t tile[64][70];
  const int bj = blockIdx.x * 64, bn = blockIdx.y * 64;
  const int tid = threadIdx.x;
  const int jl = tid & 63, nq = tid >> 6;
  const int j = bj + jl;
  const int b = j / C, c = j - b * C;
#pragma unroll
  for (int r = 0; r < 16; ++r) {
    const int node = bn + nq + r * 4;
    const int idx = node * 64 + b;
    ushort_t uv;
    if (WITHX && c == 0) {
      uv = f2bh(x[((size_t)b * T_ + t) * NN + node]);
      Agh[(size_t)idx * KP] = uv;
    } else {
      uv = Agh[(size_t)idx * KP + c];
    }
    tile[nq + r * 4][jl] = uv;
  }
  __syncthreads();
  const int nl = tid & 63, jq = tid >> 6;
#pragma unroll
  for (int r = 0; r < 16; ++r) {
    const int jj = bj + jq + r * 4;
    XTh[(size_t)jj * NN + bn + nl] = tile[nl][jq + r * 4];
  }
}

// ---------------------------------------------------------------------------
// Graph conv: 128 nodes x 128 j x 1 plane (grid z), BK=64, XOR-swizzled LDS.
// 4 waves in 2x2; wave tile 64x64 as 4mt x 4nt of 16x16 MFMAs.
// Epilogue: gather 128x128 bf16 output tile in LDS (chunk-XOR swizzle),
// then j-major coalesced global write (full cachelines).
// slice1 = S1@X; slice2 = M@X - X (exact -I before staging).
template <int C, int KP>
__global__ void graph_mfma_kernel(const ushort_t* __restrict__ S1h,
                                  const ushort_t* __restrict__ Mh,
                                  const ushort_t* __restrict__ XTh,
                                  ushort_t* __restrict__ Agh) {
  constexpr int W = B_ * C;
  const int bj = blockIdx.x * 128;
  if (bj >= W) return;  // padding block (keeps gridDim.x % 8 == 0)
  const int bn = blockIdx.y * 128;
  const int s = blockIdx.z;  // plane: 0=S1, 1=M
  const ushort_t* Ag = s ? Mh : S1h;
  __shared__ __align__(16) ushort_t sLDS[2 * 128 * 64];  // 32 KB
  ushort_t* sA = sLDS;
  ushort_t* sB = sLDS + 128 * 64;
  const int tid = threadIdx.x;
  const int w = tid >> 6, lane = tid & 63;
  const int row = lane & 15, kq = lane >> 4;
  const int srow8 = lane >> 3;   // row within 8-row stage chunk
  const int sslot = lane & 7;    // LDS 16B slot within row
  const int mrow = (w >> 1) * 64, jcol = (w & 1) * 64;

  f32x4 acc[4][4] = {};  // [mt][nt]
  for (int k0 = 0; k0 < NN; k0 += 64) {
    // 32 stage chunks of 8 rows (16 A + 16 B); wave w stages 8.
#pragma unroll
    for (int t2 = 0; t2 < 8; ++t2) {
      const int cid = w + t2 * 4;
      if (cid < 16) {
        const int grow = cid * 8 + srow8;
        const int gch = sslot ^ (grow & 7);
        gload_lds16(Ag + (size_t)(bn + grow) * NN + k0 + gch * 8, sA + cid * 512);
      } else {
        const int rb = cid - 16;
        const int brow = rb * 8 + srow8;
        const int gch = sslot ^ (brow & 7);
        gload_lds16(XTh + (size_t)(bj + brow) * NN + k0 + gch * 8, sB + rb * 512);
      }
    }
    __syncthreads();
#pragma unroll
    for (int kk = 0; kk < 2; ++kk) {
      short8 a[4];
#pragma unroll
      for (int mt = 0; mt < 4; ++mt) {
        const int r = mrow + mt * 16 + row;
        const int chunk = (kk * 4 + kq) ^ (r & 7);
        a[mt] = *(const short8*)(sA + r * 64 + chunk * 8);
      }
#pragma unroll
      for (int nt = 0; nt < 4; ++nt) {
        const int r = jcol + nt * 16 + row;
        const int chunk = (kk * 4 + kq) ^ (r & 7);
        const short8 bh = *(const short8*)(sB + r * 64 + chunk * 8);
#pragma unroll
        for (int mt = 0; mt < 4; ++mt)
          acc[mt][nt] = __builtin_amdgcn_mfma_f32_16x16x32_bf16(a[mt], bh, acc[mt][nt], 0, 0, 0);
      }
    }
    __syncthreads();
  }
  // Stage output tile to LDS (bf16, chunk-XOR swizzle on bits 4-5 of j_l).
  // D mapping (16x16): col (=j_l) = lane&15 part, row (=node_l) = kq*4+reg.
  ushort_t* sOut = sLDS;  // 128*128 ushorts = 32 KB (staging space reused)
#pragma unroll
  for (int nt = 0; nt < 4; ++nt) {
    const int j_l = jcol + nt * 16 + row;
#pragma unroll
    for (int mt = 0; mt < 4; ++mt) {
      const int nl0 = mrow + mt * 16 + kq * 4;
      float sub[4] = {0.f, 0.f, 0.f, 0.f};
      if (s == 1) {  // exact -X for the Chebyshev -I term
        const ushort_t* xp = XTh + (size_t)(bj + j_l) * NN + bn + nl0;
#pragma unroll
        for (int r = 0; r < 4; ++r) sub[r] = bh2f(xp[r]);
      }
#pragma unroll
      for (int r = 0; r < 4; ++r) {
        const int nl = nl0 + r;
        const int sw = ((nl >> 2) & 3) << 4;
        sOut[nl * 128 + (j_l ^ sw)] = f2bh(acc[mt][nt][r] - sub[r]);
      }
    }
  }
  __syncthreads();
  // Coalesced j-major write: 16 iters x (8 nodes x 128 j); lanes sweep j.
  const int slice_off = (s + 1) * C;
  const int jl0 = (tid & 31) * 4;
#pragma unroll
  for (int it = 0; it < 16; ++it) {
    const int nl = it * 8 + (tid >> 5);
    const int node = bn + nl;
    const int sw = ((nl >> 2) & 3) << 4;
    const short4v v4 = *(const short4v*)(sOut + nl * 128 + (jl0 ^ sw));
#pragma unroll
    for (int i = 0; i < 4; ++i) {
      const int j = bj + jl0 + i;
      if (j < W) {
        const int b = j / C, c = j - b * C;
        Agh[(size_t)(node * 64 + b) * KP + slice_off + c] = (ushort_t)v4[i];
      }
    }
  }
}

// ---------------------------------------------------------------------------
// Dense on MFMA, 64-row tiles, BK=32, T2-swizzled, GRU fused.
// MODE 2 (gate): col<H: z=sig(v) -> Agh[CO+col]=bf16(z*h). col>=H: rbuf=bf16(sig).
// MODE 1 (up): hnew = r*h + (1-r)*tanh(v); hstate & Agh[CO+col] updated.
// MODE 3 (dec up+proj): MODE 1 + row-dot with pW -> out/go/Agh[0,1] for t+1.
template <int KP, int NO, int NOP, int MODE, int H, int CO>
__global__ void dense_mfma_kernel(ushort_t* __restrict__ Agh,
                                  const ushort_t* __restrict__ Wth,
                                  const float* __restrict__ bias,
                                  float* __restrict__ hstate,
                                  ushort_t* __restrict__ rbuf,
                                  const float* __restrict__ pW,
                                  const float* __restrict__ pb,
                                  const float* __restrict__ ycov,
                                  float* __restrict__ outp,
                                  float* __restrict__ go,
                                  int t) {
  constexpr int NFR = NO / 16;
  __shared__ __align__(16) ushort_t sAh[64 * 32];
  __shared__ __align__(16) ushort_t sBh[NOP * 32];
  const int row0 = blockIdx.x * 64;
  const int tid = threadIdx.x;
  const int w = tid >> 6, lane = tid & 63;
  const int col16 = lane & 15, four = lane >> 4;
  const int srow = lane >> 2;
  const int scol = ((lane & 3) ^ ((srow >> 1) & 3)) * 8;  // pre-swizzled source
  const int kqs = (four ^ ((col16 >> 1) & 3)) * 8;        // swizzled read slot
  f32x4 acc[NFR] = {};
  for (int k0 = 0; k0 < KP; k0 += 32) {
    {  // A: 4 chunks of 16 rows; wave w stages chunk w
      const size_t g = (size_t)(row0 + w * 16 + srow) * KP + k0 + scol;
      gload_lds16(Agh + g, sAh + w * 512);
    }
    for (int c = w; c < NOP / 16; c += 4) {
      const size_t g = (size_t)(c * 16 + srow) * KP + k0 + scol;
      gload_lds16(Wth + g, sBh + c * 512);
    }
    __syncthreads();
    const short8 ah = *(const short8*)(sAh + (w * 16 + col16) * 32 + kqs);
#pragma unroll
    for (int nt = 0; nt < NFR; ++nt) {
      const int r = (nt * 16 + col16) * 32 + kqs;
      const short8 bh = *(const short8*)(sBh + r);
      acc[nt] = __builtin_amdgcn_mfma_f32_16x16x32_bf16(ah, bh, acc[nt], 0, 0, 0);
    }
    __syncthreads();
  }
  float pgo[4];
  if (MODE == 3) {
#pragma unroll
    for (int r = 0; r < 4; ++r) pgo[r] = 0.f;
  }
#pragma unroll
  for (int nt = 0; nt < NFR; ++nt) {
    const int col = nt * 16 + col16;
    const float bv = bias[col];
    const float pwv = (MODE == 3) ? pW[col] : 0.f;
    const int rbase = row0 + w * 16 + four * 4;
#pragma unroll
    for (int r = 0; r < 4; ++r) {
      const int row = rbase + r;
      const float v = acc[nt][r] + bv;
      if (MODE == 2) {
        const float sg = 1.f / (1.f + expf(-v));
        if (col < H) {
          const float hv = hstate[(size_t)row * H + col];
          Agh[(size_t)row * KP + CO + col] = f2bh(sg * hv);
        } else {
          rbuf[(size_t)row * H + (col - H)] = f2bh(sg);
        }
      } else {
        const float rg = bh2f(rbuf[(size_t)row * H + col]);
        const float hv = hstate[(size_t)row * H + col];
        const float hnew = rg * hv + (1.f - rg) * tanhf(v);
        hstate[(size_t)row * H + col] = hnew;
        Agh[(size_t)row * KP + CO + col] = f2bh(hnew);
        if (MODE == 3) pgo[r] += hnew * pwv;
      }
    }
  }
  if (MODE == 3) {
#pragma unroll
    for (int r = 0; r < 4; ++r) {
      float v = pgo[r];
      v += __shfl_xor(v, 1);
      v += __shfl_xor(v, 2);
      v += __shfl_xor(v, 4);
      v += __shfl_xor(v, 8);
      v += pb[0];
      if (col16 == 0) {
        const int row = row0 + w * 16 + four * 4 + r;
        const int n = row >> 6, b = row & 63;
        outp[((size_t)b * HOR_ + t) * NN + n] = v;
        go[row] = v;
        if (t + 1 < HOR_) {
          Agh[(size_t)row * KP + 0] = f2bh(v);
          Agh[(size_t)row * KP + 1] = f2bh(ycov[((size_t)b * HOR_ + t + 1) * NN + n]);
        }
      }
    }
  }
}

// ---------------------------------------------------------------------------
// attention + prototype + W_E (bf16 hi/lo) + h0 build, fused. Thread per (n,b).
__global__ void attn_kernel(const float* __restrict__ h, const float* __restrict__ Wq,
                            const float* __restrict__ Mem, const float* __restrict__ FCE,
                            float* __restrict__ hB, ushort_t* __restrict__ WEh,
                            ushort_t* __restrict__ WEl) {
  __shared__ float sWq[64 * 32];
  __shared__ float sM[10 * 32];
  __shared__ float sF[32 * 8];
  const int tid = threadIdx.x;
  for (int i = tid; i < 64 * 32; i += 256) sWq[i] = Wq[i];
  for (int i = tid; i < 10 * 32; i += 256) sM[i] = Mem[i];
  for (int i = tid; i < 32 * 8; i += 256) sF[i] = FCE[i];
  __syncthreads();
  const int idx = blockIdx.x * 256 + tid;
  const float* hp = h + (size_t)idx * 64;
  float* hd = hB + (size_t)idx * 96;
  float q[32] = {};
  for (int i0 = 0; i0 < 16; ++i0) {
    const float4 h4 = *(const float4*)(hp + i0 * 4);
#pragma unroll
    for (int jj = 0; jj < 4; ++jj) {
      const float hv = ((const float*)&h4)[jj];
      hd[i0 * 4 + jj] = hv;  // h0 = [h, proto]
      const int i = i0 * 4 + jj;
#pragma unroll
      for (int c = 0; c < 32; ++c) q[c] += hv * sWq[i * 32 + c];
    }
  }
  float lg[10];
  float mx = -1e30f;
#pragma unroll
  for (int m = 0; m < 10; ++m) {
    float s = 0.f;
#pragma unroll
    for (int c = 0; c < 32; ++c) s += q[c] * sM[m * 32 + c];
    lg[m] = s;
    mx = fmaxf(mx, s);
  }
  float den = 0.f;
#pragma unroll
  for (int m = 0; m < 10; ++m) { lg[m] = expf(lg[m] - mx); den += lg[m]; }
  const float inv = 1.f / den;
  float p[32] = {};
#pragma unroll
  for (int m = 0; m < 10; ++m) {
    const float a = lg[m] * inv;
#pragma unroll
    for (int c = 0; c < 32; ++c) p[c] += a * sM[m * 32 + c];
  }
#pragma unroll
  for (int c = 0; c < 32; ++c) hd[64 + c] = p[c];
#pragma unroll
  for (int e = 0; e < 8; ++e) {
    float s = 0.f;
#pragma unroll
    for (int c = 0; c < 32; ++c) s += p[c] * sF[c * 8 + e];
    ushort_t hi, lo;
    split_bf16(s, hi, lo);
    WEh[(size_t)idx * 8 + e] = hi;
    WEl[(size_t)idx * 8 + e] = lo;
  }
}

// ---------------------------------------------------------------------------
extern "C" void kernel_launch(void* const* d_in, const int* in_sizes, int n_in,
                              void* d_out, int out_size, void* d_ws, size_t ws_size,
                              hipStream_t stream) {
  const float* x    = (const float*)d_in[0];
  const float* ycov = (const float*)d_in[1];
  const float* emb  = (const float*)d_in[2];
  const float* egW  = (const float*)d_in[3];
  const float* egb  = (const float*)d_in[4];
  const float* euW  = (const float*)d_in[5];
  const float* eub  = (const float*)d_in[6];
  const float* Mem  = (const float*)d_in[7];
  const float* Wq   = (const float*)d_in[8];
  const float* FCE  = (const float*)d_in[9];
  const float* dgW  = (const float*)d_in[10];
  const float* dgb  = (const float*)d_in[11];
  const float* duW  = (const float*)d_in[12];
  const float* dub  = (const float*)d_in[13];
  const float* pW   = (const float*)d_in[14];
  const float* pb   = (const float*)d_in[15];
  float* out = (float*)d_out;

  char* w = (char*)d_ws;
  auto alloc = [&](size_t bytes) {
    void* p = (void*)w;
    w += (bytes + 255) & ~(size_t)255;
    return p;
  };
  float* S1   = (float*)alloc((size_t)NN * NN * 4);
  float* hA   = (float*)alloc((size_t)NN * B_ * 64 * 4);
  float* hB   = (float*)alloc((size_t)NN * B_ * 96 * 4);
  float* go   = (float*)alloc((size_t)NN * B_ * 4);
  ushort_t* rbuf = (ushort_t*)alloc((size_t)NN * B_ * 96 * 2);
  ushort_t* WEh = (ushort_t*)alloc((size_t)NN * 512 * 2);
  ushort_t* WEl = (ushort_t*)alloc((size_t)NN * 512 * 2);
  ushort_t* S1h = (ushort_t*)alloc((size_t)NN * NN * 2);
  ushort_t* S1l = (ushort_t*)alloc((size_t)NN * NN * 2);
  ushort_t* Mh  = (ushort_t*)alloc((size_t)NN * NN * 2);
  ushort_t* STh = (ushort_t*)alloc((size_t)NN * NN * 2);
  ushort_t* STl = (ushort_t*)alloc((size_t)NN * NN * 2);
  ushort_t* XTh = (ushort_t*)alloc((size_t)B_ * 98 * NN * 2);
  ushort_t* Agh = (ushort_t*)alloc((size_t)NN * B_ * 320 * 2);
  ushort_t* WtegH = (ushort_t*)alloc(128 * 224 * 2);
  ushort_t* WteuH = (ushort_t*)alloc(64 * 224 * 2);
  ushort_t* WtdgH = (ushort_t*)alloc(192 * 320 * 2);
  ushort_t* WtduH = (ushort_t*)alloc(128 * 320 * 2);
  (void)ws_size; (void)in_sizes; (void)n_in; (void)out_size;

  const dim3 blk(256);

  // ---- weight transposes + buffer init (pad regions must be defined) ----
  wt_kernel<<<(128 * 224 + 255) / 256, blk, 0, stream>>>(egW, WtegH, 195, 128, 224, 128);
  wt_kernel<<<(64 * 224 + 255) / 256, blk, 0, stream>>>(euW, WteuH, 195, 64, 224, 64);
  wt_kernel<<<(192 * 320 + 255) / 256, blk, 0, stream>>>(dgW, WtdgH, 294, 192, 320, 192);
  wt_kernel<<<(128 * 320 + 255) / 256, blk, 0, stream>>>(duW, WtduH, 294, 96, 320, 128);
  hipMemsetAsync(Agh, 0, (size_t)NN * B_ * 320 * 2, stream);
  hipMemsetAsync(hA, 0, (size_t)NN * B_ * 64 * 4, stream);
  hipMemsetAsync(go, 0, (size_t)NN * B_ * 4, stream);

  // ---- encoder supports ----
  gemm_nt_kernel<<<dim3(16, 16), blk, 0, stream>>>(emb, emb, S1, NN, 8);
  relu_softmax_kernel<<<NN, blk, 0, stream>>>(S1, S1h, S1l);
  st_kernel<<<dim3(16, 16), blk, 0, stream>>>(S1, STh, STl);
  cheb_mfma_kernel<<<dim3(16, 32), blk, 0, stream>>>(S1h, S1l, STh, STl, Mh);

  // ---- encoder scan ----  (W_enc = 4160; 128-j tiles: 33 live, padded 40; KP=224)
  for (int t = 0; t < T_; ++t) {
    if (t == 0) {
      prep_kernel<65, 224, 0><<<dim3(65, 16), blk, 0, stream>>>(x, nullptr, hA, Agh, XTh);
    } else {
      xt_kernel<65, 224, true><<<dim3(65, 16), blk, 0, stream>>>(Agh, XTh, x, t);
    }
    graph_mfma_kernel<65, 224><<<dim3(40, 8, 2), blk, 0, stream>>>(S1h, Mh, XTh, Agh);
    dense_mfma_kernel<224, 128, 128, 2, 64, 1><<<1024, blk, 0, stream>>>(
        Agh, WtegH, egb, hA, rbuf, nullptr, nullptr, nullptr, nullptr, nullptr, 0);
    xt_kernel<65, 224, false><<<dim3(65, 16), blk, 0, stream>>>(Agh, XTh, nullptr, 0);
    graph_mfma_kernel<65, 224><<<dim3(40, 8, 2), blk, 0, stream>>>(S1h, Mh, XTh, Agh);
    dense_mfma_kernel<224, 64, 64, 1, 64, 1><<<1024, blk, 0, stream>>>(
        Agh, WteuH, eub, hA, rbuf, nullptr, nullptr, nullptr, nullptr, nullptr, 0);
  }

  // ---- attention / memory / decoder supports ----
  attn_kernel<<<256, blk, 0, stream>>>(hA, Wq, Mem, FCE, hB, WEh, WEl);
  we_syrk_kernel<<<dim3(16, 32), blk, 0, stream>>>(WEh, WEl, S1);
  relu_softmax_kernel<<<NN, blk, 0, stream>>>(S1, S1h, S1l);
  st_kernel<<<dim3(16, 16), blk, 0, stream>>>(S1, STh, STl);
  cheb_mfma_kernel<<<dim3(16, 32), blk, 0, stream>>>(S1h, S1l, STh, STl, Mh);

  // ---- decoder scan ----  (W_dec = 6272; 128-j tiles: 49 live, padded 56; KP=320)
  for (int t = 0; t < HOR_; ++t) {
    if (t == 0) {
      prep_kernel<98, 320, 2><<<dim3(98, 16), blk, 0, stream>>>(go, ycov, hB, Agh, XTh);
    } else {
      xt_kernel<98, 320, false><<<dim3(98, 16), blk, 0, stream>>>(Agh, XTh, nullptr, 0);
    }
    graph_mfma_kernel<98, 320><<<dim3(56, 8, 2), blk, 0, stream>>>(S1h, Mh, XTh, Agh);
    dense_mfma_kernel<320, 192, 192, 2, 96, 2><<<1024, blk, 0, stream>>>(
        Agh, WtdgH, dgb, hB, rbuf, nullptr, nullptr, nullptr, nullptr, nullptr, 0);
    xt_kernel<98, 320, false><<<dim3(98, 16), blk, 0, stream>>>(Agh, XTh, nullptr, 0);
    graph_mfma_kernel<98, 320><<<dim3(56, 8, 2), blk, 0, stream>>>(S1h, Mh, XTh, Agh);
    dense_mfma_kernel<320, 96, 128, 3, 96, 2><<<1024, blk, 0, stream>>>(
        Agh, WtduH, dub, hB, rbuf, pW, pb, ycov, out, go, t);
  }
}

// Round 25
// 3358.736 us; speedup vs baseline: 1.0502x; 1.0502x over previous
//
#include <hip/hip_runtime.h>
#include <hip/hip_bf16.h>

// MMGCRN on MFMA (r23 configuration — measured best, 3359 us).
// Graph: 128n x 128j x plane blocks, 64x64 wave tiles built from 16x16 MFMAs
// (0.5 ds_reads/MFMA); slice2 = M@X - X (M=2S^2, exact -I in epilogue).
// Dense: A(bf16) x W(bf16), 64-row tiles BK=32, GRU fused; dec-up fuses proj.
// Agh slice-0 incremental. XOR-swizzled LDS. B=64,T=12,N=1024,HOR=12.
constexpr int B_ = 64, T_ = 12, NN = 1024, HOR_ = 12;

typedef __attribute__((ext_vector_type(8))) short short8;   // 8 bf16 (4 VGPRs)
typedef __attribute__((ext_vector_type(4))) float f32x4;    // MFMA C/D frag
typedef unsigned short ushort_t;

static __device__ inline ushort_t f2bh(float v) {
  __hip_bfloat16 h = __float2bfloat16(v);
  return *reinterpret_cast<ushort_t*>(&h);
}
static __device__ inline float bh2f(ushort_t u) {
  __hip_bfloat16 h = *reinterpret_cast<__hip_bfloat16*>(&u);
  return __bfloat162float(h);
}
static __device__ inline void split_bf16(float v, ushort_t& hi, ushort_t& lo) {
  hi = f2bh(v);
  lo = f2bh(v - bh2f(hi));
}

// async global->LDS, 16B per lane (LDS dest = wave-uniform base + lane*16).
static __device__ inline void gload_lds16(const ushort_t* g, ushort_t* l) {
  __builtin_amdgcn_global_load_lds(
      (const __attribute__((address_space(1))) unsigned int*)g,
      (__attribute__((address_space(3))) unsigned int*)l, 16, 0, 0);
}

// ---------------------------------------------------------------------------
// C = A (M x Kd) @ B (Ncol x Kd)^T, row-major, 64x64 tile, 4x4/thread. fp32.
// (only the tiny emb syrk, Kd=8)
__global__ void gemm_nt_kernel(const float* __restrict__ A, const float* __restrict__ Bm,
                               float* __restrict__ C, int Ncol, int Kd) {
  __shared__ float As[16][68];
  __shared__ float Bs[16][68];
  const int bm = blockIdx.y * 64, bn = blockIdx.x * 64;
  const int tid = threadIdx.x;
  const int tx = tid & 15, ty = tid >> 4;
  float acc[4][4] = {};
  for (int k0 = 0; k0 < Kd; k0 += 16) {
#pragma unroll
    for (int r = 0; r < 4; ++r) {
      const int m = (tid >> 4) + r * 16;
      const int kk = tid & 15;
      const int k = k0 + kk;
      As[kk][m] = (k < Kd) ? A[(size_t)(bm + m) * Kd + k] : 0.f;
      Bs[kk][m] = (k < Kd) ? Bm[(size_t)(bn + m) * Kd + k] : 0.f;
    }
    __syncthreads();
#pragma unroll
    for (int kk = 0; kk < 16; ++kk) {
      float a[4], b[4];
#pragma unroll
      for (int i = 0; i < 4; ++i) a[i] = As[kk][ty * 4 + i];
#pragma unroll
      for (int j = 0; j < 4; ++j) b[j] = Bs[kk][tx * 4 + j];
#pragma unroll
      for (int i = 0; i < 4; ++i)
#pragma unroll
        for (int j = 0; j < 4; ++j) acc[i][j] += a[i] * b[j];
    }
    __syncthreads();
  }
#pragma unroll
  for (int i = 0; i < 4; ++i)
#pragma unroll
    for (int j = 0; j < 4; ++j)
      C[(size_t)(bm + ty * 4 + i) * Ncol + bn + tx * 4 + j] = acc[i][j];
}

// ---------------------------------------------------------------------------
// In-place row softmax(relu(x)) over 1024 cols; also emits bf16 hi/lo split.
__global__ void relu_softmax_kernel(float* __restrict__ S, ushort_t* __restrict__ Sh,
                                    ushort_t* __restrict__ Sl) {
  const int row = blockIdx.x;
  float* r = S + (size_t)row * NN;
  const int tid = threadIdx.x;  // 256
  float v[4];
  float mx = 0.f;
#pragma unroll
  for (int j = 0; j < 4; ++j) {
    float xv = fmaxf(r[tid + j * 256], 0.f);
    v[j] = xv;
    mx = fmaxf(mx, xv);
  }
#pragma unroll
  for (int off = 1; off < 64; off <<= 1) mx = fmaxf(mx, __shfl_xor(mx, off));
  __shared__ float sred[4];
  const int wv = tid >> 6;
  if ((tid & 63) == 0) sred[wv] = mx;
  __syncthreads();
  mx = fmaxf(fmaxf(sred[0], sred[1]), fmaxf(sred[2], sred[3]));
  __syncthreads();
  float s = 0.f;
#pragma unroll
  for (int j = 0; j < 4; ++j) { v[j] = expf(v[j] - mx); s += v[j]; }
#pragma unroll
  for (int off = 1; off < 64; off <<= 1) s += __shfl_xor(s, off);
  if ((tid & 63) == 0) sred[wv] = s;
  __syncthreads();
  s = sred[0] + sred[1] + sred[2] + sred[3];
  const float inv = 1.f / s;
#pragma unroll
  for (int j = 0; j < 4; ++j) {
    const float sv = v[j] * inv;
    const size_t e = (size_t)row * NN + tid + j * 256;
    r[tid + j * 256] = sv;
    ushort_t hi, lo;
    split_bf16(sv, hi, lo);
    Sh[e] = hi;
    Sl[e] = lo;
  }
}

// ---------------------------------------------------------------------------
// ST = S^T, bf16 hi/lo split. LDS-tiled 64x64, both sides coalesced.
__global__ void st_kernel(const float* __restrict__ S, ushort_t* __restrict__ STh,
                          ushort_t* __restrict__ STl) {
  __shared__ float tile[64][65];
  const int bx = blockIdx.x * 64, by = blockIdx.y * 64;
  const int tid = threadIdx.x;
  const int cl = tid & 63, rq = tid >> 6;
#pragma unroll
  for (int r = 0; r < 16; ++r) {
    const int rr = rq + r * 4;
    tile[rr][cl] = S[(size_t)(by + rr) * NN + bx + cl];
  }
  __syncthreads();
#pragma unroll
  for (int r = 0; r < 16; ++r) {
    const int rr = rq + r * 4;
    const float v = tile[cl][rr];  // = S[by+cl][bx+rr]
    ushort_t hi, lo;
    split_bf16(v, hi, lo);
    STh[(size_t)(bx + rr) * NN + by + cl] = hi;
    STl[(size_t)(bx + rr) * NN + by + cl] = lo;
  }
}

// ---------------------------------------------------------------------------
// M = 2*S@S on MFMA, bf16x3 (A=S1 hi/lo, B=ST hi/lo), out single bf16 plane.
// Tile 32n x 64j, BK=64, grid (16,32). XOR-swizzled LDS.
__global__ void cheb_mfma_kernel(const ushort_t* __restrict__ S1h,
                                 const ushort_t* __restrict__ S1l,
                                 const ushort_t* __restrict__ STh,
                                 const ushort_t* __restrict__ STl,
                                 ushort_t* __restrict__ Mh) {
  __shared__ __align__(16) ushort_t sA[2 * 32 * 64];  // 8 KB
  __shared__ __align__(16) ushort_t sB[2 * 64 * 64];  // 16 KB
  const int bj = blockIdx.x * 64, bn = blockIdx.y * 32;
  const int tid = threadIdx.x;
  const int w = tid >> 6, lane = tid & 63;
  const int row = lane & 15, kq = lane >> 4;
  const int srow8 = lane >> 3, sslot = lane & 7;
  f32x4 acc[2] = {};
  for (int k0 = 0; k0 < NN; k0 += 64) {
#pragma unroll
    for (int t2 = 0; t2 < 2; ++t2) {  // A: 8 chunks, wave stages 2
      const int c = w + t2 * 4, p = c >> 2, i = c & 3;
      const int grow = i * 8 + srow8;
      const int gch = sslot ^ (grow & 7);
      const ushort_t* src = (p ? S1l : S1h) + (size_t)(bn + grow) * NN + k0 + gch * 8;
      gload_lds16(src, sA + p * 2048 + i * 512);
    }
#pragma unroll
    for (int t2 = 0; t2 < 4; ++t2) {  // B: 16 chunks, wave stages 4
      const int c2 = w + t2 * 4, p = c2 >> 3, rb = c2 & 7;
      const int grow = rb * 8 + srow8;
      const int gch = sslot ^ (grow & 7);
      const ushort_t* src = (p ? STl : STh) + (size_t)(bj + grow) * NN + k0 + gch * 8;
      gload_lds16(src, sB + p * 4096 + rb * 512);
    }
    __syncthreads();
#pragma unroll
    for (int kk = 0; kk < 2; ++kk) {
      const int rB = w * 16 + row;
      const int chB = ((kk * 4 + kq) ^ (rB & 7)) * 8;
      const short8 bh = *(const short8*)(sB + rB * 64 + chB);
      const short8 bl = *(const short8*)(sB + 4096 + rB * 64 + chB);
#pragma unroll
      for (int mt = 0; mt < 2; ++mt) {
        const int rA = mt * 16 + row;
        const int chA = ((kk * 4 + kq) ^ (rA & 7)) * 8;
        const short8 ah = *(const short8*)(sA + rA * 64 + chA);
        const short8 al = *(const short8*)(sA + 2048 + rA * 64 + chA);
        acc[mt] = __builtin_amdgcn_mfma_f32_16x16x32_bf16(ah, bh, acc[mt], 0, 0, 0);
        acc[mt] = __builtin_amdgcn_mfma_f32_16x16x32_bf16(ah, bl, acc[mt], 0, 0, 0);
        acc[mt] = __builtin_amdgcn_mfma_f32_16x16x32_bf16(al, bh, acc[mt], 0, 0, 0);
      }
    }
    __syncthreads();
  }
  const int j = bj + w * 16 + row;
#pragma unroll
  for (int mt = 0; mt < 2; ++mt) {
    const int node0 = bn + mt * 16 + kq * 4;
#pragma unroll
    for (int r = 0; r < 4; ++r)
      Mh[(size_t)(node0 + r) * NN + j] = f2bh(2.f * acc[mt][r]);
  }
}

// ---------------------------------------------------------------------------
// S1out = WE @ WE^T on MFMA, bf16x3 (WE hi/lo, K=512), fp32 out.
// Tile 32 x 64, BK=64, grid (16, 32). XOR-swizzled LDS.
__global__ void we_syrk_kernel(const ushort_t* __restrict__ WEh,
                               const ushort_t* __restrict__ WEl,
                               float* __restrict__ S1out) {
  __shared__ __align__(16) ushort_t sA[2 * 32 * 64];  // 8 KB
  __shared__ __align__(16) ushort_t sB[2 * 64 * 64];  // 16 KB
  const int bj = blockIdx.x * 64, bn = blockIdx.y * 32;
  const int tid = threadIdx.x;
  const int w = tid >> 6, lane = tid & 63;
  const int row = lane & 15, kq = lane >> 4;
  const int srow8 = lane >> 3, sslot = lane & 7;
  f32x4 acc[2] = {};
  for (int k0 = 0; k0 < 512; k0 += 64) {
#pragma unroll
    for (int t2 = 0; t2 < 6; ++t2) {  // 24 chunks: 8 A + 16 B
      const int cid = w + t2 * 4;
      if (cid < 8) {
        const int p = cid >> 2, i = cid & 3;
        const int grow = i * 8 + srow8;
        const int gch = sslot ^ (grow & 7);
        const ushort_t* src = (p ? WEl : WEh) + (size_t)(bn + grow) * 512 + k0 + gch * 8;
        gload_lds16(src, sA + p * 2048 + i * 512);
      } else {
        const int c2 = cid - 8, p = c2 >> 3, rb = c2 & 7;
        const int grow = rb * 8 + srow8;
        const int gch = sslot ^ (grow & 7);
        const ushort_t* src = (p ? WEl : WEh) + (size_t)(bj + grow) * 512 + k0 + gch * 8;
        gload_lds16(src, sB + p * 4096 + rb * 512);
      }
    }
    __syncthreads();
#pragma unroll
    for (int kk = 0; kk < 2; ++kk) {
      const int rB = w * 16 + row;
      const int chB = ((kk * 4 + kq) ^ (rB & 7)) * 8;
      const short8 bh = *(const short8*)(sB + rB * 64 + chB);
      const short8 bl = *(const short8*)(sB + 4096 + rB * 64 + chB);
#pragma unroll
      for (int mt = 0; mt < 2; ++mt) {
        const int rA = mt * 16 + row;
        const int chA = ((kk * 4 + kq) ^ (rA & 7)) * 8;
        const short8 ah = *(const short8*)(sA + rA * 64 + chA);
        const short8 al = *(const short8*)(sA + 2048 + rA * 64 + chA);
        acc[mt] = __builtin_amdgcn_mfma_f32_16x16x32_bf16(ah, bh, acc[mt], 0, 0, 0);
        acc[mt] = __builtin_amdgcn_mfma_f32_16x16x32_bf16(ah, bl, acc[mt], 0, 0, 0);
        acc[mt] = __builtin_amdgcn_mfma_f32_16x16x32_bf16(al, bh, acc[mt], 0, 0, 0);
      }
    }
    __syncthreads();
  }
  const int j = bj + w * 16 + row;
#pragma unroll
  for (int mt = 0; mt < 2; ++mt) {
    const int node0 = bn + mt * 16 + kq * 4;
#pragma unroll
    for (int r = 0; r < 4; ++r)
      S1out[(size_t)(node0 + r) * NN + j] = acc[mt][r];
  }
}

// ---------------------------------------------------------------------------
// Wt[no][k] = W[k][no], plain bf16, zero-padded to [NOP][KP].
__global__ void wt_kernel(const float* __restrict__ W, ushort_t* __restrict__ Wth,
                          int KK, int NO, int KP, int NOP) {
  const int e = blockIdx.x * 256 + threadIdx.x;
  if (e >= NOP * KP) return;
  const int no = e / KP, k = e - no * KP;
  const float v = (no < NO && k < KK) ? W[(size_t)k * NO + no] : 0.f;
  Wth[e] = f2bh(v);
}

// ---------------------------------------------------------------------------
// prep (t=0 only): build cell input; write Agh slice0 + XTh.
// MODE 0: enc build [x_0, h]; MODE 2: dec build [go, yc_0, h].
template <int C, int KP, int MODE>
__global__ void prep_kernel(const float* __restrict__ src0, const float* __restrict__ src1,
                            const float* __restrict__ hst,
                            ushort_t* __restrict__ Agh, ushort_t* __restrict__ XTh) {
  __shared__ float tile[64][65];
  const int bj = blockIdx.x * 64, bn = blockIdx.y * 64;
  const int tid = threadIdx.x;
  const int jl = tid & 63, nq = tid >> 6;
  const int j = bj + jl;
  const int b = j / C, c = j - b * C;
#pragma unroll
  for (int r = 0; r < 16; ++r) {
    const int node = bn + nq + r * 4;
    const int idx = node * 64 + b;
    float v;
    if (MODE == 0) {
      v = (c == 0) ? src0[((size_t)b * T_) * NN + node]
                   : hst[(size_t)idx * 64 + (c - 1)];
    } else {
      v = (c == 0) ? src0[idx]
        : (c == 1) ? src1[((size_t)b * HOR_) * NN + node]
                   : hst[(size_t)idx * 96 + (c - 2)];
    }
    tile[nq + r * 4][jl] = v;
    Agh[(size_t)idx * KP + c] = f2bh(v);
  }
  __syncthreads();
  const int nl = tid & 63, jq = tid >> 6;
#pragma unroll
  for (int r = 0; r < 16; ++r) {
    const int jj = bj + jq + r * 4;
    XTh[(size_t)jj * NN + bn + nl] = f2bh(tile[nl][jq + r * 4]);
  }
}

// ---------------------------------------------------------------------------
// xt: transpose Agh slice0 -> XTh. WITHX: c==0 comes from x[t] (also stored).
template <int C, int KP, bool WITHX>
__global__ void xt_kernel(ushort_t* __restrict__ Agh, ushort_t* __restrict__ XTh,
                          const float* __restrict__ x, int t) {
  __shared__ ushort_t tile[64][70];
  const int bj = blockIdx.x * 64, bn = blockIdx.y * 64;
  const int tid = threadIdx.x;
  const int jl = tid & 63, nq = tid >> 6;
  const int j = bj + jl;
  const int b = j / C, c = j - b * C;
#pragma unroll
  for (int r = 0; r < 16; ++r) {
    const int node = bn + nq + r * 4;
    const int idx = node * 64 + b;
    ushort_t uv;
    if (WITHX && c == 0) {
      uv = f2bh(x[((size_t)b * T_ + t) * NN + node]);
      Agh[(size_t)idx * KP] = uv;
    } else {
      uv = Agh[(size_t)idx * KP + c];
    }
    tile[nq + r * 4][jl] = uv;
  }
  __syncthreads();
  const int nl = tid & 63, jq = tid >> 6;
#pragma unroll
  for (int r = 0; r < 16; ++r) {
    const int jj = bj + jq + r * 4;
    XTh[(size_t)jj * NN + bn + nl] = tile[nl][jq + r * 4];
  }
}

// ---------------------------------------------------------------------------
// Graph conv: 128 nodes x 128 j x 1 plane (grid z), BK=64, XOR-swizzled LDS.
// 4 waves in 2x2; wave tile 64x64 as 4mt x 4nt of 16x16 MFMAs
// (16 ds_read_b128 per 32 MFMA = 0.5 reads/MFMA).
// slice1 = S1@X; slice2 = M@X - X (exact -I in fp32 epilogue).
template <int C, int KP>
__global__ void graph_mfma_kernel(const ushort_t* __restrict__ S1h,
                                  const ushort_t* __restrict__ Mh,
                                  const ushort_t* __restrict__ XTh,
                                  ushort_t* __restrict__ Agh) {
  constexpr int W = B_ * C;
  const int bj = blockIdx.x * 128;
  if (bj >= W) return;  // padding block (keeps gridDim.x % 8 == 0)
  const int bn = blockIdx.y * 128;
  const int s = blockIdx.z;  // plane: 0=S1, 1=M
  const ushort_t* Ag = s ? Mh : S1h;
  __shared__ __align__(16) ushort_t sA[128 * 64];  // 16 KB
  __shared__ __align__(16) ushort_t sB[128 * 64];  // 16 KB
  const int tid = threadIdx.x;
  const int w = tid >> 6, lane = tid & 63;
  const int row = lane & 15, kq = lane >> 4;
  const int srow8 = lane >> 3;   // row within 8-row stage chunk
  const int sslot = lane & 7;    // LDS 16B slot within row
  const int mrow = (w >> 1) * 64, jcol = (w & 1) * 64;

  f32x4 acc[4][4] = {};  // [mt][nt]
  for (int k0 = 0; k0 < NN; k0 += 64) {
    // 32 stage chunks of 8 rows (16 A + 16 B); wave w stages 8.
#pragma unroll
    for (int t2 = 0; t2 < 8; ++t2) {
      const int cid = w + t2 * 4;
      if (cid < 16) {
        const int grow = cid * 8 + srow8;
        const int gch = sslot ^ (grow & 7);
        gload_lds16(Ag + (size_t)(bn + grow) * NN + k0 + gch * 8, sA + cid * 512);
      } else {
        const int rb = cid - 16;
        const int brow = rb * 8 + srow8;
        const int gch = sslot ^ (brow & 7);
        gload_lds16(XTh + (size_t)(bj + brow) * NN + k0 + gch * 8, sB + rb * 512);
      }
    }
    __syncthreads();
#pragma unroll
    for (int kk = 0; kk < 2; ++kk) {
      short8 a[4];
#pragma unroll
      for (int mt = 0; mt < 4; ++mt) {
        const int r = mrow + mt * 16 + row;
        const int chunk = (kk * 4 + kq) ^ (r & 7);
        a[mt] = *(const short8*)(sA + r * 64 + chunk * 8);
      }
#pragma unroll
      for (int nt = 0; nt < 4; ++nt) {
        const int r = jcol + nt * 16 + row;
        const int chunk = (kk * 4 + kq) ^ (r & 7);
        const short8 bh = *(const short8*)(sB + r * 64 + chunk * 8);
#pragma unroll
        for (int mt = 0; mt < 4; ++mt)
          acc[mt][nt] = __builtin_amdgcn_mfma_f32_16x16x32_bf16(a[mt], bh, acc[mt][nt], 0, 0, 0);
      }
    }
    __syncthreads();
  }
  // D mapping (16x16): col (=j) = lane&15, row (=node) = (lane>>4)*4 + reg.
  const int slice_off = (s + 1) * C;
#pragma unroll
  for (int nt = 0; nt < 4; ++nt) {
    const int j = bj + jcol + nt * 16 + row;
    if (j < W) {
      const int b = j / C, c = j - b * C;
      const size_t coloff = (size_t)(slice_off + c);
#pragma unroll
      for (int mt = 0; mt < 4; ++mt) {
        const int node0 = bn + mrow + mt * 16 + kq * 4;
        float sub[4] = {0.f, 0.f, 0.f, 0.f};
        if (s == 1) {  // exact -X for the Chebyshev -I term
          const ushort_t* xp = XTh + (size_t)j * NN + node0;
#pragma unroll
          for (int r = 0; r < 4; ++r) sub[r] = bh2f(xp[r]);
        }
#pragma unroll
        for (int r = 0; r < 4; ++r) {
          const size_t a2 = (size_t)((node0 + r) * 64 + b) * KP + coloff;
          Agh[a2] = f2bh(acc[mt][nt][r] - sub[r]);
        }
      }
    }
  }
}

// ---------------------------------------------------------------------------
// Dense on MFMA, 64-row tiles, BK=32, T2-swizzled, GRU fused.
// MODE 2 (gate): col<H: z=sig(v) -> Agh[CO+col]=bf16(z*h). col>=H: rbuf=bf16(sig).
// MODE 1 (up): hnew = r*h + (1-r)*tanh(v); hstate & Agh[CO+col] updated.
// MODE 3 (dec up+proj): MODE 1 + row-dot with pW -> out/go/Agh[0,1] for t+1.
template <int KP, int NO, int NOP, int MODE, int H, int CO>
__global__ void dense_mfma_kernel(ushort_t* __restrict__ Agh,
                                  const ushort_t* __restrict__ Wth,
                                  const float* __restrict__ bias,
                                  float* __restrict__ hstate,
                                  ushort_t* __restrict__ rbuf,
                                  const float* __restrict__ pW,
                                  const float* __restrict__ pb,
                                  const float* __restrict__ ycov,
                                  float* __restrict__ outp,
                                  float* __restrict__ go,
                                  int t) {
  constexpr int NFR = NO / 16;
  __shared__ __align__(16) ushort_t sAh[64 * 32];
  __shared__ __align__(16) ushort_t sBh[NOP * 32];
  const int row0 = blockIdx.x * 64;
  const int tid = threadIdx.x;
  const int w = tid >> 6, lane = tid & 63;
  const int col16 = lane & 15, four = lane >> 4;
  const int srow = lane >> 2;
  const int scol = ((lane & 3) ^ ((srow >> 1) & 3)) * 8;  // pre-swizzled source
  const int kqs = (four ^ ((col16 >> 1) & 3)) * 8;        // swizzled read slot
  f32x4 acc[NFR] = {};
  for (int k0 = 0; k0 < KP; k0 += 32) {
    {  // A: 4 chunks of 16 rows; wave w stages chunk w
      const size_t g = (size_t)(row0 + w * 16 + srow) * KP + k0 + scol;
      gload_lds16(Agh + g, sAh + w * 512);
    }
    for (int c = w; c < NOP / 16; c += 4) {
      const size_t g = (size_t)(c * 16 + srow) * KP + k0 + scol;
      gload_lds16(Wth + g, sBh + c * 512);
    }
    __syncthreads();
    const short8 ah = *(const short8*)(sAh + (w * 16 + col16) * 32 + kqs);
#pragma unroll
    for (int nt = 0; nt < NFR; ++nt) {
      const int r = (nt * 16 + col16) * 32 + kqs;
      const short8 bh = *(const short8*)(sBh + r);
      acc[nt] = __builtin_amdgcn_mfma_f32_16x16x32_bf16(ah, bh, acc[nt], 0, 0, 0);
    }
    __syncthreads();
  }
  float pgo[4];
  if (MODE == 3) {
#pragma unroll
    for (int r = 0; r < 4; ++r) pgo[r] = 0.f;
  }
#pragma unroll
  for (int nt = 0; nt < NFR; ++nt) {
    const int col = nt * 16 + col16;
    const float bv = bias[col];
    const float pwv = (MODE == 3) ? pW[col] : 0.f;
    const int rbase = row0 + w * 16 + four * 4;
#pragma unroll
    for (int r = 0; r < 4; ++r) {
      const int row = rbase + r;
      const float v = acc[nt][r] + bv;
      if (MODE == 2) {
        const float sg = 1.f / (1.f + expf(-v));
        if (col < H) {
          const float hv = hstate[(size_t)row * H + col];
          Agh[(size_t)row * KP + CO + col] = f2bh(sg * hv);
        } else {
          rbuf[(size_t)row * H + (col - H)] = f2bh(sg);
        }
      } else {
        const float rg = bh2f(rbuf[(size_t)row * H + col]);
        const float hv = hstate[(size_t)row * H + col];
        const float hnew = rg * hv + (1.f - rg) * tanhf(v);
        hstate[(size_t)row * H + col] = hnew;
        Agh[(size_t)row * KP + CO + col] = f2bh(hnew);
        if (MODE == 3) pgo[r] += hnew * pwv;
      }
    }
  }
  if (MODE == 3) {
#pragma unroll
    for (int r = 0; r < 4; ++r) {
      float v = pgo[r];
      v += __shfl_xor(v, 1);
      v += __shfl_xor(v, 2);
      v += __shfl_xor(v, 4);
      v += __shfl_xor(v, 8);
      v += pb[0];
      if (col16 == 0) {
        const int row = row0 + w * 16 + four * 4 + r;
        const int n = row >> 6, b = row & 63;
        outp[((size_t)b * HOR_ + t) * NN + n] = v;
        go[row] = v;
        if (t + 1 < HOR_) {
          Agh[(size_t)row * KP + 0] = f2bh(v);
          Agh[(size_t)row * KP + 1] = f2bh(ycov[((size_t)b * HOR_ + t + 1) * NN + n]);
        }
      }
    }
  }
}

// ---------------------------------------------------------------------------
// attention + prototype + W_E (bf16 hi/lo) + h0 build, fused. Thread per (n,b).
__global__ void attn_kernel(const float* __restrict__ h, const float* __restrict__ Wq,
                            const float* __restrict__ Mem, const float* __restrict__ FCE,
                            float* __restrict__ hB, ushort_t* __restrict__ WEh,
                            ushort_t* __restrict__ WEl) {
  __shared__ float sWq[64 * 32];
  __shared__ float sM[10 * 32];
  __shared__ float sF[32 * 8];
  const int tid = threadIdx.x;
  for (int i = tid; i < 64 * 32; i += 256) sWq[i] = Wq[i];
  for (int i = tid; i < 10 * 32; i += 256) sM[i] = Mem[i];
  for (int i = tid; i < 32 * 8; i += 256) sF[i] = FCE[i];
  __syncthreads();
  const int idx = blockIdx.x * 256 + tid;
  const float* hp = h + (size_t)idx * 64;
  float* hd = hB + (size_t)idx * 96;
  float q[32] = {};
  for (int i0 = 0; i0 < 16; ++i0) {
    const float4 h4 = *(const float4*)(hp + i0 * 4);
#pragma unroll
    for (int jj = 0; jj < 4; ++jj) {
      const float hv = ((const float*)&h4)[jj];
      hd[i0 * 4 + jj] = hv;  // h0 = [h, proto]
      const int i = i0 * 4 + jj;
#pragma unroll
      for (int c = 0; c < 32; ++c) q[c] += hv * sWq[i * 32 + c];
    }
  }
  float lg[10];
  float mx = -1e30f;
#pragma unroll
  for (int m = 0; m < 10; ++m) {
    float s = 0.f;
#pragma unroll
    for (int c = 0; c < 32; ++c) s += q[c] * sM[m * 32 + c];
    lg[m] = s;
    mx = fmaxf(mx, s);
  }
  float den = 0.f;
#pragma unroll
  for (int m = 0; m < 10; ++m) { lg[m] = expf(lg[m] - mx); den += lg[m]; }
  const float inv = 1.f / den;
  float p[32] = {};
#pragma unroll
  for (int m = 0; m < 10; ++m) {
    const float a = lg[m] * inv;
#pragma unroll
    for (int c = 0; c < 32; ++c) p[c] += a * sM[m * 32 + c];
  }
#pragma unroll
  for (int c = 0; c < 32; ++c) hd[64 + c] = p[c];
#pragma unroll
  for (int e = 0; e < 8; ++e) {
    float s = 0.f;
#pragma unroll
    for (int c = 0; c < 32; ++c) s += p[c] * sF[c * 8 + e];
    ushort_t hi, lo;
    split_bf16(s, hi, lo);
    WEh[(size_t)idx * 8 + e] = hi;
    WEl[(size_t)idx * 8 + e] = lo;
  }
}

// ---------------------------------------------------------------------------
extern "C" void kernel_launch(void* const* d_in, const int* in_sizes, int n_in,
                              void* d_out, int out_size, void* d_ws, size_t ws_size,
                              hipStream_t stream) {
  const float* x    = (const float*)d_in[0];
  const float* ycov = (const float*)d_in[1];
  const float* emb  = (const float*)d_in[2];
  const float* egW  = (const float*)d_in[3];
  const float* egb  = (const float*)d_in[4];
  const float* euW  = (const float*)d_in[5];
  const float* eub  = (const float*)d_in[6];
  const float* Mem  = (const float*)d_in[7];
  const float* Wq   = (const float*)d_in[8];
  const float* FCE  = (const float*)d_in[9];
  const float* dgW  = (const float*)d_in[10];
  const float* dgb  = (const float*)d_in[11];
  const float* duW  = (const float*)d_in[12];
  const float* dub  = (const float*)d_in[13];
  const float* pW   = (const float*)d_in[14];
  const float* pb   = (const float*)d_in[15];
  float* out = (float*)d_out;

  char* w = (char*)d_ws;
  auto alloc = [&](size_t bytes) {
    void* p = (void*)w;
    w += (bytes + 255) & ~(size_t)255;
    return p;
  };
  float* S1   = (float*)alloc((size_t)NN * NN * 4);
  float* hA   = (float*)alloc((size_t)NN * B_ * 64 * 4);
  float* hB   = (float*)alloc((size_t)NN * B_ * 96 * 4);
  float* go   = (float*)alloc((size_t)NN * B_ * 4);
  ushort_t* rbuf = (ushort_t*)alloc((size_t)NN * B_ * 96 * 2);
  ushort_t* WEh = (ushort_t*)alloc((size_t)NN * 512 * 2);
  ushort_t* WEl = (ushort_t*)alloc((size_t)NN * 512 * 2);
  ushort_t* S1h = (ushort_t*)alloc((size_t)NN * NN * 2);
  ushort_t* S1l = (ushort_t*)alloc((size_t)NN * NN * 2);
  ushort_t* Mh  = (ushort_t*)alloc((size_t)NN * NN * 2);
  ushort_t* STh = (ushort_t*)alloc((size_t)NN * NN * 2);
  ushort_t* STl = (ushort_t*)alloc((size_t)NN * NN * 2);
  ushort_t* XTh = (ushort_t*)alloc((size_t)B_ * 98 * NN * 2);
  ushort_t* Agh = (ushort_t*)alloc((size_t)NN * B_ * 320 * 2);
  ushort_t* WtegH = (ushort_t*)alloc(128 * 224 * 2);
  ushort_t* WteuH = (ushort_t*)alloc(64 * 224 * 2);
  ushort_t* WtdgH = (ushort_t*)alloc(192 * 320 * 2);
  ushort_t* WtduH = (ushort_t*)alloc(128 * 320 * 2);
  (void)ws_size; (void)in_sizes; (void)n_in; (void)out_size;

  const dim3 blk(256);

  // ---- weight transposes + buffer init (pad regions must be defined) ----
  wt_kernel<<<(128 * 224 + 255) / 256, blk, 0, stream>>>(egW, WtegH, 195, 128, 224, 128);
  wt_kernel<<<(64 * 224 + 255) / 256, blk, 0, stream>>>(euW, WteuH, 195, 64, 224, 64);
  wt_kernel<<<(192 * 320 + 255) / 256, blk, 0, stream>>>(dgW, WtdgH, 294, 192, 320, 192);
  wt_kernel<<<(128 * 320 + 255) / 256, blk, 0, stream>>>(duW, WtduH, 294, 96, 320, 128);
  hipMemsetAsync(Agh, 0, (size_t)NN * B_ * 320 * 2, stream);
  hipMemsetAsync(hA, 0, (size_t)NN * B_ * 64 * 4, stream);
  hipMemsetAsync(go, 0, (size_t)NN * B_ * 4, stream);

  // ---- encoder supports ----
  gemm_nt_kernel<<<dim3(16, 16), blk, 0, stream>>>(emb, emb, S1, NN, 8);
  relu_softmax_kernel<<<NN, blk, 0, stream>>>(S1, S1h, S1l);
  st_kernel<<<dim3(16, 16), blk, 0, stream>>>(S1, STh, STl);
  cheb_mfma_kernel<<<dim3(16, 32), blk, 0, stream>>>(S1h, S1l, STh, STl, Mh);

  // ---- encoder scan ----  (W_enc = 4160; 128-j tiles: 33 live, padded 40; KP=224)
  for (int t = 0; t < T_; ++t) {
    if (t == 0) {
      prep_kernel<65, 224, 0><<<dim3(65, 16), blk, 0, stream>>>(x, nullptr, hA, Agh, XTh);
    } else {
      xt_kernel<65, 224, true><<<dim3(65, 16), blk, 0, stream>>>(Agh, XTh, x, t);
    }
    graph_mfma_kernel<65, 224><<<dim3(40, 8, 2), blk, 0, stream>>>(S1h, Mh, XTh, Agh);
    dense_mfma_kernel<224, 128, 128, 2, 64, 1><<<1024, blk, 0, stream>>>(
        Agh, WtegH, egb, hA, rbuf, nullptr, nullptr, nullptr, nullptr, nullptr, 0);
    xt_kernel<65, 224, false><<<dim3(65, 16), blk, 0, stream>>>(Agh, XTh, nullptr, 0);
    graph_mfma_kernel<65, 224><<<dim3(40, 8, 2), blk, 0, stream>>>(S1h, Mh, XTh, Agh);
    dense_mfma_kernel<224, 64, 64, 1, 64, 1><<<1024, blk, 0, stream>>>(
        Agh, WteuH, eub, hA, rbuf, nullptr, nullptr, nullptr, nullptr, nullptr, 0);
  }

  // ---- attention / memory / decoder supports ----
  attn_kernel<<<256, blk, 0, stream>>>(hA, Wq, Mem, FCE, hB, WEh, WEl);
  we_syrk_kernel<<<dim3(16, 32), blk, 0, stream>>>(WEh, WEl, S1);
  relu_softmax_kernel<<<NN, blk, 0, stream>>>(S1, S1h, S1l);
  st_kernel<<<dim3(16, 16), blk, 0, stream>>>(S1, STh, STl);
  cheb_mfma_kernel<<<dim3(16, 32), blk, 0, stream>>>(S1h, S1l, STh, STl, Mh);

  // ---- decoder scan ----  (W_dec = 6272; 128-j tiles: 49 live, padded 56; KP=320)
  for (int t = 0; t < HOR_; ++t) {
    if (t == 0) {
      prep_kernel<98, 320, 2><<<dim3(98, 16), blk, 0, stream>>>(go, ycov, hB, Agh, XTh);
    } else {
      xt_kernel<98, 320, false><<<dim3(98, 16), blk, 0, stream>>>(Agh, XTh, nullptr, 0);
    }
    graph_mfma_kernel<98, 320><<<dim3(56, 8, 2), blk, 0, stream>>>(S1h, Mh, XTh, Agh);
    dense_mfma_kernel<320, 192, 192, 2, 96, 2><<<1024, blk, 0, stream>>>(
        Agh, WtdgH, dgb, hB, rbuf, nullptr, nullptr, nullptr, nullptr, nullptr, 0);
    xt_kernel<98, 320, false><<<dim3(98, 16), blk, 0, stream>>>(Agh, XTh, nullptr, 0);
    graph_mfma_kernel<98, 320><<<dim3(56, 8, 2), blk, 0, stream>>>(S1h, Mh, XTh, Agh);
    dense_mfma_kernel<320, 96, 128, 3, 96, 2><<<1024, blk, 0, stream>>>(
        Agh, WtduH, dub, hB, rbuf, pW, pb, ycov, out, go, t);
  }
}